// Round 11
// baseline (986.993 us; speedup 1.0000x reference)
//
#include <hip/hip_runtime.h>
#include <hip/hip_fp16.h>

#define FDIM 64
#define BLK 256
#define NCOPY 8

typedef float f32x4 __attribute__((ext_vector_type(4)));

// Pass 1: scatter-sum into XCD-private copies using workgroup-scope f32
// atomics. All writers of copy k are on XCD k (selected by the hardware
// XCC id), so the RMW executes coherently in that XCD's L2 (write-back),
// avoiding the ~1.25 TB/s memory-side atomic write-through wall.
__global__ void dmpnn_scatter_xcd(const float4* __restrict__ edges4,
                                  const int* __restrict__ recv,
                                  float* __restrict__ copies,
                                  long long total /* = M * 16 */,
                                  long long cstride /* floats per copy */) {
    long long tid = (long long)blockIdx.x * blockDim.x + threadIdx.x;
    if (tid >= total) return;
    int e = (int)(tid >> 4);
    int q = (int)(tid & 15);
    float4 v = edges4[tid];
    int node = recv[e];
    unsigned xcc;
    asm volatile("s_getreg_b32 %0, hwreg(HW_REG_XCC_ID)" : "=s"(xcc));
    float* dst = copies + (size_t)(xcc & (NCOPY - 1)) * cstride
               + ((size_t)node << 6) + (q << 2);
    __hip_atomic_fetch_add(dst + 0, v.x, __ATOMIC_RELAXED, __HIP_MEMORY_SCOPE_WORKGROUP);
    __hip_atomic_fetch_add(dst + 1, v.y, __ATOMIC_RELAXED, __HIP_MEMORY_SCOPE_WORKGROUP);
    __hip_atomic_fetch_add(dst + 2, v.z, __ATOMIC_RELAXED, __HIP_MEMORY_SCOPE_WORKGROUP);
    __hip_atomic_fetch_add(dst + 3, v.w, __ATOMIC_RELAXED, __HIP_MEMORY_SCOPE_WORKGROUP);
}

// Reduce the NCOPY private copies into pooled (streaming, coalesced).
__global__ void dmpnn_reduce(const float* __restrict__ copies,
                             float4* __restrict__ pooled4,
                             int totalQ /* = N * 16 */,
                             long long cstrideQ /* float4s per copy */) {
    int t = blockIdx.x * blockDim.x + threadIdx.x;
    if (t >= totalQ) return;
    const f32x4* c4 = (const f32x4*)copies;
    f32x4 acc = __builtin_nontemporal_load(&c4[t]);
    #pragma unroll
    for (int c = 1; c < NCOPY; ++c)
        acc += __builtin_nontemporal_load(&c4[(long long)c * cstrideQ + t]);
    float4 r; r.x = acc.x; r.y = acc.y; r.z = acc.z; r.w = acc.w;
    pooled4[t] = r;   // plain store: keep pooled L2/LLC-resident for pass 2
}

// Pass 2: out[e] = pooled[send[e]] - edges[pair[e]], NT output stores.
__global__ void dmpnn_gather_sub_f32(const float4* __restrict__ pooled4,
                                     const float4* __restrict__ edges4,
                                     const int* __restrict__ send,
                                     const int* __restrict__ pair,
                                     float4* __restrict__ out4,
                                     long long total /* = M * 16 */) {
    long long tid = (long long)blockIdx.x * blockDim.x + threadIdx.x;
    if (tid >= total) return;
    int e = (int)(tid >> 4);
    int q = (int)(tid & 15);
    float4 a = pooled4[(long long)send[e] * 16 + q];
    float4 b = edges4[(long long)pair[e] * 16 + q];
    f32x4 r;
    r.x = a.x - b.x; r.y = a.y - b.y; r.z = a.z - b.z; r.w = a.w - b.w;
    __builtin_nontemporal_store(r, (f32x4*)&out4[tid]);
}

// ---------------- fallback (small ws): R9 packed-atomic path ----------------
__global__ void dmpnn_scatter_h2(const float4* __restrict__ edges4,
                                 const int* __restrict__ recv,
                                 __half2* __restrict__ pooled,
                                 long long total) {
    long long tid = (long long)blockIdx.x * blockDim.x + threadIdx.x;
    if (tid >= total) return;
    int e = (int)(tid >> 4);
    int g = (int)(tid & 15);
    float4 v = edges4[tid];
    int node = recv[e];
    __half2* dst = &pooled[((long long)node << 5) + (g << 1)];
    unsafeAtomicAdd(dst + 0, __floats2half2_rn(v.x, v.y));
    unsafeAtomicAdd(dst + 1, __floats2half2_rn(v.z, v.w));
}

__global__ void dmpnn_gather_sub_h2(const __half2* __restrict__ pooled,
                                    const float4* __restrict__ edges4,
                                    const int* __restrict__ send,
                                    const int* __restrict__ pair,
                                    float4* __restrict__ out4,
                                    long long total) {
    long long tid = (long long)blockIdx.x * blockDim.x + threadIdx.x;
    if (tid >= total) return;
    int e = (int)(tid >> 4);
    int q = (int)(tid & 15);
    const __half2* ph = &pooled[((long long)send[e] << 5) + (q << 1)];
    float2 a0 = __half22float2(ph[0]);
    float2 a1 = __half22float2(ph[1]);
    float4 b = edges4[(long long)pair[e] * 16 + q];
    f32x4 r;
    r.x = a0.x - b.x; r.y = a0.y - b.y; r.z = a1.x - b.z; r.w = a1.y - b.w;
    __builtin_nontemporal_store(r, (f32x4*)&out4[tid]);
}

extern "C" void kernel_launch(void* const* d_in, const int* in_sizes, int n_in,
                              void* d_out, int out_size, void* d_ws, size_t ws_size,
                              hipStream_t stream) {
    const float* edges      = (const float*)d_in[1];
    const int*   edge_index = (const int*)d_in[2];   // [2, M] flat
    const int*   edge_pairs = (const int*)d_in[3];   // [1, M] flat

    const int N = in_sizes[0] / FDIM;   // 50000
    const int M = in_sizes[1] / FDIM;   // 1000000

    const int* recv = edge_index;
    const int* send = edge_index + M;

    long long cstride  = (long long)N * FDIM;        // floats per copy
    long long total16  = (long long)M * 16;
    unsigned  grid16   = (unsigned)((total16 + BLK - 1) / BLK);
    int       totalQ   = N * 16;
    unsigned  gridQ    = (unsigned)((totalQ + BLK - 1) / BLK);

    // ws: copies[NCOPY][N*FDIM] f32 | pooled[N*FDIM] f32
    size_t need = ((size_t)NCOPY + 1) * (size_t)cstride * sizeof(float);

    if (ws_size >= need) {
        float* copies = (float*)d_ws;
        float* pooled = copies + (size_t)NCOPY * cstride;

        (void)hipMemsetAsync(copies, 0, (size_t)NCOPY * cstride * sizeof(float), stream);

        dmpnn_scatter_xcd<<<dim3(grid16), dim3(BLK), 0, stream>>>(
            (const float4*)edges, recv, copies, total16, cstride);

        dmpnn_reduce<<<dim3(gridQ), dim3(BLK), 0, stream>>>(
            copies, (float4*)pooled, totalQ, cstride / 4);

        dmpnn_gather_sub_f32<<<dim3(grid16), dim3(BLK), 0, stream>>>(
            (const float4*)pooled, (const float4*)edges, send, edge_pairs,
            (float4*)d_out, total16);
    } else {
        __half2* pooled = (__half2*)d_ws;   // 6.4 MB
        (void)hipMemsetAsync(pooled, 0, (size_t)N * FDIM * sizeof(__half), stream);
        dmpnn_scatter_h2<<<dim3(grid16), dim3(BLK), 0, stream>>>(
            (const float4*)edges, recv, pooled, total16);
        dmpnn_gather_sub_h2<<<dim3(grid16), dim3(BLK), 0, stream>>>(
            pooled, (const float4*)edges, send, edge_pairs,
            (float4*)d_out, total16);
    }
}

// Round 12
// 375.772 us; speedup vs baseline: 2.6266x; 2.6266x over previous
//
#include <hip/hip_runtime.h>
#include <hip/hip_fp16.h>

#define FDIM 64
#define BLK 256

typedef float f32x4 __attribute__((ext_vector_type(4)));

// ---------------- build: hist -> bump-alloc -> fill ----------------
__global__ void dmpnn_hist(const int* __restrict__ recv, int* __restrict__ counts, int M) {
    int e = blockIdx.x * blockDim.x + threadIdx.x;
    if (e >= M) return;
    atomicAdd(&counts[recv[e]], 1);
}

// Block-local exclusive scan + one global bump per block. Region order is
// nondeterministic, but pooled sums are order-independent (f32 adds,
// rounding jitter well under threshold).
__global__ void dmpnn_alloc(const int* __restrict__ counts,
                            int* __restrict__ cursor,
                            int* __restrict__ gcounter, int N) {
    __shared__ int s[BLK];
    __shared__ int sbase;
    int t = blockIdx.x * BLK + threadIdx.x;
    int c = (t < N) ? counts[t] : 0;
    s[threadIdx.x] = c;
    __syncthreads();
    for (int d = 1; d < BLK; d <<= 1) {
        int v = (threadIdx.x >= (unsigned)d) ? s[threadIdx.x - d] : 0;
        __syncthreads();
        s[threadIdx.x] += v;
        __syncthreads();
    }
    if (threadIdx.x == BLK - 1) sbase = atomicAdd(gcounter, s[BLK - 1]);
    __syncthreads();
    if (t < N) cursor[t] = sbase + s[threadIdx.x] - c;
}

__global__ void dmpnn_fill(const int* __restrict__ recv,
                           int* __restrict__ cursor,
                           int* __restrict__ perm,
                           int* __restrict__ nodeOf, int M) {
    int e = blockIdx.x * blockDim.x + threadIdx.x;
    if (e >= M) return;
    int n = recv[e];
    int pos = atomicAdd(&cursor[n], 1);
    perm[pos] = e;
    nodeOf[pos] = n;
}

// ---------------- flat aggregate: gather_sub's exact shape ----------------
// One 16-lane group per perm slot (no per-thread loop). Block = 16 slots.
// LDS segmented tree-reduce across slots (node-runs are contiguous since
// each node owns one perm region), then ONE atomic row-flush per run:
// ~112K flushes x 256 B ~= 29 MB atomic payload (9x under the 1.26 TB/s
// write-through wall) vs 256 MB for the naive scatter.
__global__ void dmpnn_aggregate(const float4* __restrict__ edges4,
                                const int* __restrict__ perm,
                                const int* __restrict__ nodeOf,
                                float* __restrict__ pooled, int M) {
    __shared__ float4 vs[16][16];   // [slot][quad] = 4 KB
    __shared__ int nd[16];

    int s = threadIdx.x >> 4;       // slot-in-block 0..15
    int q = threadIdx.x & 15;
    long long slot = (long long)blockIdx.x * 16 + s;
    bool valid = slot < M;

    int n = -1;
    float4 v = make_float4(0.f, 0.f, 0.f, 0.f);
    if (valid) {
        int e = perm[slot];         // broadcast across the 16 lanes
        n = nodeOf[slot];
        v = edges4[(long long)e * 16 + q];
    }
    if (q == 0) nd[s] = n;
    vs[s][q] = v;
    __syncthreads();

    // Segmented inclusive scan over slots (equal nd => same contiguous run).
    #pragma unroll
    for (int d = 1; d < 16; d <<= 1) {
        bool take = (s >= d) && (nd[s] == nd[s - d]) && (nd[s] != -1);
        float4 add = take ? vs[s - d][q] : make_float4(0.f, 0.f, 0.f, 0.f);
        __syncthreads();
        if (take) {
            v.x += add.x; v.y += add.y; v.z += add.z; v.w += add.w;
            vs[s][q] = v;
        }
        __syncthreads();
    }

    // Run-end slots flush the reduced row.
    bool end = valid && (s == 15 || nd[s + 1] != nd[s]);
    if (end) {
        float* dst = &pooled[(long long)n * FDIM + (q << 2)];
        atomicAdd(dst + 0, v.x);
        atomicAdd(dst + 1, v.y);
        atomicAdd(dst + 2, v.z);
        atomicAdd(dst + 3, v.w);
    }
}

// ---------------- Pass 2: gather + subtract, NT output stores ----------------
__global__ void dmpnn_gather_sub_f32(const float4* __restrict__ pooled4,
                                     const float4* __restrict__ edges4,
                                     const int* __restrict__ send,
                                     const int* __restrict__ pair,
                                     float4* __restrict__ out4,
                                     long long total /* = M * 16 */) {
    long long tid = (long long)blockIdx.x * blockDim.x + threadIdx.x;
    if (tid >= total) return;
    int e = (int)(tid >> 4);
    int q = (int)(tid & 15);
    float4 a = pooled4[(long long)send[e] * 16 + q];
    float4 b = edges4[(long long)pair[e] * 16 + q];
    f32x4 r;
    r.x = a.x - b.x; r.y = a.y - b.y; r.z = a.z - b.z; r.w = a.w - b.w;
    __builtin_nontemporal_store(r, (f32x4*)&out4[tid]);
}

// ---------------- fallback (small ws): R9 packed-atomic path ----------------
__global__ void dmpnn_scatter_h2(const float4* __restrict__ edges4,
                                 const int* __restrict__ recv,
                                 __half2* __restrict__ pooled,
                                 long long total) {
    long long tid = (long long)blockIdx.x * blockDim.x + threadIdx.x;
    if (tid >= total) return;
    int e = (int)(tid >> 4);
    int g = (int)(tid & 15);
    float4 v = edges4[tid];
    int node = recv[e];
    __half2* dst = &pooled[((long long)node << 5) + (g << 1)];
    unsafeAtomicAdd(dst + 0, __floats2half2_rn(v.x, v.y));
    unsafeAtomicAdd(dst + 1, __floats2half2_rn(v.z, v.w));
}

__global__ void dmpnn_gather_sub_h2(const __half2* __restrict__ pooled,
                                    const float4* __restrict__ edges4,
                                    const int* __restrict__ send,
                                    const int* __restrict__ pair,
                                    float4* __restrict__ out4,
                                    long long total) {
    long long tid = (long long)blockIdx.x * blockDim.x + threadIdx.x;
    if (tid >= total) return;
    int e = (int)(tid >> 4);
    int q = (int)(tid & 15);
    const __half2* ph = &pooled[((long long)send[e] << 5) + (q << 1)];
    float2 a0 = __half22float2(ph[0]);
    float2 a1 = __half22float2(ph[1]);
    float4 b = edges4[(long long)pair[e] * 16 + q];
    f32x4 r;
    r.x = a0.x - b.x; r.y = a0.y - b.y; r.z = a1.x - b.z; r.w = a1.y - b.w;
    __builtin_nontemporal_store(r, (f32x4*)&out4[tid]);
}

extern "C" void kernel_launch(void* const* d_in, const int* in_sizes, int n_in,
                              void* d_out, int out_size, void* d_ws, size_t ws_size,
                              hipStream_t stream) {
    const float* edges      = (const float*)d_in[1];
    const int*   edge_index = (const int*)d_in[2];   // [2, M] flat
    const int*   edge_pairs = (const int*)d_in[3];   // [1, M] flat

    const int N = in_sizes[0] / FDIM;   // 50000
    const int M = in_sizes[1] / FDIM;   // 1000000

    const int* recv = edge_index;
    const int* send = edge_index + M;

    const size_t Np = (size_t)((N + 3) & ~3);
    const size_t Mp = (size_t)((M + 15) & ~15);

    // ws (ints): counts[Np] | gcounter[4] | cursor[Np] | perm[Mp] | nodeOf[Mp]
    //            then pooled: N*FDIM f32
    size_t need = (2 * Np + 4 + 2 * Mp) * sizeof(int)
                + (size_t)N * FDIM * sizeof(float);

    long long total16 = (long long)M * 16;
    unsigned grid16 = (unsigned)((total16 + BLK - 1) / BLK);

    if (ws_size >= need) {
        int*   counts   = (int*)d_ws;
        int*   gcounter = counts + Np;
        int*   cursor   = gcounter + 4;
        int*   perm     = cursor + Np;
        int*   nodeOf   = perm + Mp;
        float* pooled   = (float*)(nodeOf + Mp);

        (void)hipMemsetAsync(counts, 0, (Np + 4) * sizeof(int), stream);
        (void)hipMemsetAsync(pooled, 0, (size_t)N * FDIM * sizeof(float), stream);

        dmpnn_hist<<<dim3((M + BLK - 1) / BLK), dim3(BLK), 0, stream>>>(recv, counts, M);
        dmpnn_alloc<<<dim3((N + BLK - 1) / BLK), dim3(BLK), 0, stream>>>(counts, cursor, gcounter, N);
        dmpnn_fill<<<dim3((M + BLK - 1) / BLK), dim3(BLK), 0, stream>>>(recv, cursor, perm, nodeOf, M);

        {
            // one block per 16 slots, one 16-lane group per slot
            unsigned blocks = (unsigned)((M + 15) / 16);
            dmpnn_aggregate<<<dim3(blocks), dim3(BLK), 0, stream>>>(
                (const float4*)edges, perm, nodeOf, pooled, M);
        }

        dmpnn_gather_sub_f32<<<dim3(grid16), dim3(BLK), 0, stream>>>(
            (const float4*)pooled, (const float4*)edges, send, edge_pairs,
            (float4*)d_out, total16);
    } else {
        __half2* pooled = (__half2*)d_ws;   // 6.4 MB
        (void)hipMemsetAsync(pooled, 0, (size_t)N * FDIM * sizeof(__half), stream);
        dmpnn_scatter_h2<<<dim3(grid16), dim3(BLK), 0, stream>>>(
            (const float4*)edges, recv, pooled, total16);
        dmpnn_gather_sub_h2<<<dim3(grid16), dim3(BLK), 0, stream>>>(
            pooled, (const float4*)edges, send, edge_pairs,
            (float4*)d_out, total16);
    }
}

// Round 13
// 299.577 us; speedup vs baseline: 3.2946x; 1.2543x over previous
//
#include <hip/hip_runtime.h>
#include <hip/hip_fp16.h>

// Best measured structure (R9: 298.3 us), reverted after CSR/XCD/LDS
// alternatives (R2,R3,R7,R10,R11,R12) all measured slower.
//
// Measured walls on MI355X (this problem):
//  - scatter: 256 MB atomic write-through at ~1.26 TB/s memory-side RMW
//    (invariant to op count / packing / row spread) -> ~203 us.
//  - gather_sub: ~470 MB HBM at ~5 TB/s (random 256 B row gathers + NT
//    stream-out) -> ~95 us.

#define FDIM 64
#define BLK 256

typedef float f32x4 __attribute__((ext_vector_type(4)));

// Pass 1: scatter-sum edges into f16x2 pooled via packed HW atomics
// (global_atomic_pk_add_f16). Thread per (edge, float4-group).
__global__ void dmpnn_scatter_h2(const float4* __restrict__ edges4,
                                 const int* __restrict__ recv,
                                 __half2* __restrict__ pooled,  // [N][32] half2
                                 long long total /* = M * 16 */) {
    long long tid = (long long)blockIdx.x * blockDim.x + threadIdx.x;
    if (tid >= total) return;
    int e = (int)(tid >> 4);
    int g = (int)(tid & 15);
    float4 v = edges4[tid];
    int node = recv[e];                       // broadcast across the 16 lanes
    __half2* dst = &pooled[((long long)node << 5) + (g << 1)];
    unsafeAtomicAdd(dst + 0, __floats2half2_rn(v.x, v.y));
    unsafeAtomicAdd(dst + 1, __floats2half2_rn(v.z, v.w));
}

// Pass 2: out[e] = pooled[send[e]] - edges[pair[e]], NT output stores.
__global__ void dmpnn_gather_sub(const __half2* __restrict__ pooled,
                                 const float4* __restrict__ edges4,
                                 const int* __restrict__ send,
                                 const int* __restrict__ pair,
                                 float4* __restrict__ out4,
                                 long long total /* = M * 16 */) {
    long long tid = (long long)blockIdx.x * blockDim.x + threadIdx.x;
    if (tid >= total) return;
    int e = (int)(tid >> 4);
    int q = (int)(tid & 15);
    int sn = send[e];
    int pe = pair[e];
    const __half2* ph = &pooled[((long long)sn << 5) + (q << 1)];
    __half2 h0 = ph[0];
    __half2 h1 = ph[1];
    float2 a0 = __half22float2(h0);
    float2 a1 = __half22float2(h1);
    float4 b = edges4[(long long)pe * 16 + q];
    f32x4 r;
    r.x = a0.x - b.x;
    r.y = a0.y - b.y;
    r.z = a1.x - b.z;
    r.w = a1.y - b.w;
    __builtin_nontemporal_store(r, (f32x4*)&out4[tid]);
}

// f32 fallback if workspace were ever too small for the half pooled buffer.
__global__ void dmpnn_scatter_add(const float* __restrict__ edges,
                                  const int* __restrict__ recv,
                                  float* __restrict__ pooled,
                                  long long total) {
    long long tid = (long long)blockIdx.x * blockDim.x + threadIdx.x;
    if (tid >= total) return;
    int e = (int)(tid >> 6);
    int f = (int)(tid & 63);
    atomicAdd(&pooled[(long long)recv[e] * FDIM + f], edges[tid]);
}

__global__ void dmpnn_gather_sub_f32(const float4* __restrict__ pooled4,
                                     const float4* __restrict__ edges4,
                                     const int* __restrict__ send,
                                     const int* __restrict__ pair,
                                     float4* __restrict__ out4,
                                     long long total) {
    long long tid = (long long)blockIdx.x * blockDim.x + threadIdx.x;
    if (tid >= total) return;
    int e = (int)(tid >> 4);
    int q = (int)(tid & 15);
    float4 a = pooled4[(long long)send[e] * 16 + q];
    float4 b = edges4[(long long)pair[e] * 16 + q];
    f32x4 r;
    r.x = a.x - b.x; r.y = a.y - b.y; r.z = a.z - b.z; r.w = a.w - b.w;
    __builtin_nontemporal_store(r, (f32x4*)&out4[tid]);
}

extern "C" void kernel_launch(void* const* d_in, const int* in_sizes, int n_in,
                              void* d_out, int out_size, void* d_ws, size_t ws_size,
                              hipStream_t stream) {
    const float* edges      = (const float*)d_in[1];
    const int*   edge_index = (const int*)d_in[2];   // [2, M] flat
    const int*   edge_pairs = (const int*)d_in[3];   // [1, M] flat

    const int N = in_sizes[0] / FDIM;   // 50000
    const int M = in_sizes[1] / FDIM;   // 1000000

    const int* recv = edge_index;
    const int* send = edge_index + M;

    size_t need_h = (size_t)N * FDIM * sizeof(__half);

    long long total16 = (long long)M * 16;
    unsigned grid16 = (unsigned)((total16 + BLK - 1) / BLK);

    if (ws_size >= need_h) {
        __half2* pooled = (__half2*)d_ws;   // [N][32] half2 = 6.4 MB

        // Zero accumulator every call (0x0000 == +0.0h).
        (void)hipMemsetAsync(pooled, 0, need_h, stream);

        dmpnn_scatter_h2<<<dim3(grid16), dim3(BLK), 0, stream>>>(
            (const float4*)edges, recv, pooled, total16);

        dmpnn_gather_sub<<<dim3(grid16), dim3(BLK), 0, stream>>>(
            pooled, (const float4*)edges, send, edge_pairs,
            (float4*)d_out, total16);
    } else {
        float* pooled = (float*)d_ws;
        (void)hipMemsetAsync(pooled, 0, (size_t)N * FDIM * sizeof(float), stream);
        long long totalS = (long long)M * FDIM;
        dmpnn_scatter_add<<<dim3((unsigned)((totalS + BLK - 1) / BLK)), dim3(BLK), 0, stream>>>(
            edges, recv, pooled, totalS);
        dmpnn_gather_sub_f32<<<dim3(grid16), dim3(BLK), 0, stream>>>(
            (const float4*)pooled, (const float4*)edges, send, edge_pairs,
            (float4*)d_out, total16);
    }
}